// Round 6
// baseline (110.105 us; speedup 1.0000x reference)
//
#include <hip/hip_runtime.h>
#include <hip/hip_bf16.h>
#include <math.h>

// Problem constants (from the reference)
#define BB 512        // batch
#define CC 1000       // classes
#define TT 64         // num param tensors
#define PSZ 500000    // elements per tensor
#define NW 9          // loss weights per tensor

#define N4 125000     // float4 per tensor
// Line = 64 float4 = 1 KB (one wave-load). 125000 float4 = 1953 lines + 8 float4.
#define LINES_T 1953
#define TAIL4_T 8     // leftover float4 per tensor (indices 124992..124999)
#define BPT 31        // blocks per tensor
#define LPB 63        // lines per block (31*63 = 1953 exactly)
#define PBLKS (TT * BPT)   // 1984

// Workspace layout (floats):
//  ws[0] = sum_b CE contribution    ws[1] = sum_b hinge row sums
//  ws[2] = sum_{b,j} logp           ws[3] = sum_b sum_j p*logp
//  ws[4] = sum_{b,j} o^2
//  ws[8 + t*4 + {0,1,2,3}] = {l1_zero, sumsq_zero, l1_pre, sumsq_pre}
#define WS_FLOATS (8 + TT * 4)

typedef float f32x4 __attribute__((ext_vector_type(4)));

__device__ __forceinline__ f32x4 ntload(const f32x4* a) {
    return __builtin_nontemporal_load(a);
}

// ---------------------------------------------------------------------------
__device__ __forceinline__ float block_reduce_sum(float v, float* scratch) {
    __syncthreads();
    for (int o = 32; o > 0; o >>= 1) v += __shfl_down(v, o);
    const int wave = threadIdx.x >> 6;
    if ((threadIdx.x & 63) == 0) scratch[wave] = v;
    __syncthreads();
    return scratch[0] + scratch[1] + scratch[2] + scratch[3];
}

__device__ __forceinline__ float block_reduce_max(float v, float* scratch) {
    __syncthreads();
    for (int o = 32; o > 0; o >>= 1) v = fmaxf(v, __shfl_down(v, o));
    const int wave = threadIdx.x >> 6;
    if ((threadIdx.x & 63) == 0) scratch[wave] = v;
    __syncthreads();
    return fmaxf(fmaxf(scratch[0], scratch[1]), fmaxf(scratch[2], scratch[3]));
}

__device__ __forceinline__ void acc4(const f32x4 a, const f32x4 c,
                                     float& l1z, float& s2z,
                                     float& l1p, float& s2p) {
    l1z += fabsf(a.x) + fabsf(a.y) + fabsf(a.z) + fabsf(a.w);
    s2z += a.x * a.x + a.y * a.y + a.z * a.z + a.w * a.w;
    const float dx = a.x - c.x, dy = a.y - c.y, dz = a.z - c.z, dw = a.w - c.w;
    l1p += fabsf(dx) + fabsf(dy) + fabsf(dz) + fabsf(dw);
    s2p += dx * dx + dy * dy + dz * dz + dw * dw;
}

// ---------------------------------------------------------------------------
// Fused kernel.
// Param path (blocks [0,1984)): each WAVE owns a contiguous run of 1 KB lines
// and reads them strictly sequentially — 8 consecutive lines from p, then the
// matching 8 from q, then consume. R5 showed block-level contiguity is worth
// +23%; this removes the last per-wave 4 KB striding.
// Logits path: blocks [1984, 2496).
// ---------------------------------------------------------------------------
__global__ __launch_bounds__(256) void fused_kernel(
        const float* __restrict__ p, const float* __restrict__ q,
        const float* __restrict__ outlog, const int* __restrict__ tgt,
        float* __restrict__ ws) {
    __shared__ float row[CC];
    __shared__ float scratch[4];

    const int bid = blockIdx.x;
    const int tid = (int)threadIdx.x;
    if (bid < PBLKS) {
        // ---------------- param-norm path (256 MB total) -------------------
        const int t  = bid / BPT;
        const int cb = bid - t * BPT;          // chunk index within tensor
        const int wave = tid >> 6;
        const int lane = tid & 63;

        const f32x4* __restrict__ pb = (const f32x4*)p + (long long)t * N4;
        const f32x4* __restrict__ qb = (const f32x4*)q + (long long)t * N4;

        // wave-contiguous line assignment: waves 0-2 get 16 lines, wave 3: 15
        const int my_l0 = cb * LPB + wave * 16;
        const int my_n  = (wave == 3) ? 15 : 16;

        float l1z = 0.f, s2z = 0.f, l1p = 0.f, s2p = 0.f;

        int i = 0;
        // groups of 8 sequential lines: 8 KB contiguous from p, 8 KB from q
        for (; i + 8 <= my_n; i += 8) {
            const f32x4* bp = pb + (long long)(my_l0 + i) * 64 + lane;
            const f32x4* bq = qb + (long long)(my_l0 + i) * 64 + lane;
            f32x4 A[8], C[8];
            #pragma unroll
            for (int k = 0; k < 8; ++k) A[k] = ntload(bp + k * 64);
            #pragma unroll
            for (int k = 0; k < 8; ++k) C[k] = ntload(bq + k * 64);
            #pragma unroll
            for (int k = 0; k < 8; ++k) acc4(A[k], C[k], l1z, s2z, l1p, s2p);
        }
        // remainder lines (wave 3: 7 lines), still sequential
        for (; i < my_n; ++i) {
            const f32x4 a = ntload(pb + (long long)(my_l0 + i) * 64 + lane);
            const f32x4 c = ntload(qb + (long long)(my_l0 + i) * 64 + lane);
            acc4(a, c, l1z, s2z, l1p, s2p);
        }
        // per-tensor tail: 8 float4 past the last full line (block 0, wave 0)
        if (cb == 0 && wave == 0 && lane < TAIL4_T) {
            const f32x4 a = ntload(pb + LINES_T * 64 + lane);
            const f32x4 c = ntload(qb + LINES_T * 64 + lane);
            acc4(a, c, l1z, s2z, l1p, s2p);
        }

        for (int o = 32; o > 0; o >>= 1) {
            l1z += __shfl_down(l1z, o);
            s2z += __shfl_down(s2z, o);
            l1p += __shfl_down(l1p, o);
            s2p += __shfl_down(s2p, o);
        }
        if (lane == 0) {
            float* base = ws + 8 + t * 4;
            atomicAdd(base + 0, l1z);
            atomicAdd(base + 1, s2z);
            atomicAdd(base + 2, l1p);
            atomicAdd(base + 3, s2p);
        }
    } else {
        // ---------------- logits path (one block per batch row) ------------
        const int b = bid - PBLKS;
        const float* __restrict__ o = outlog + (long long)b * CC;

        float sq = 0.f;
        for (int j = tid; j < CC; j += 256) {
            const float v = o[j];
            row[j] = v;
            sq += v * v;
        }
        __syncthreads();

        float m = -3.402823466e+38f;
        for (int j = tid; j < CC; j += 256) m = fmaxf(m, row[j]);
        m = block_reduce_max(m, scratch);

        float se = 0.f;
        for (int j = tid; j < CC; j += 256) se += __expf(row[j] - m);
        se = block_reduce_sum(se, scratch);
        const float logZ = m + __logf(se);

        const int tg = tgt[b];
        const float ot = row[tg];

        float ent = 0.f, lps = 0.f, hin = 0.f;
        for (int j = tid; j < CC; j += 256) {
            const float lp = row[j] - logZ;
            ent += __expf(lp) * lp;
            lps += lp;
            const float mg = 1.f - ot + row[j];
            if (j != tg && mg > 0.f) hin += mg;
        }
        sq  = block_reduce_sum(sq, scratch);
        ent = block_reduce_sum(ent, scratch);
        lps = block_reduce_sum(lps, scratch);
        hin = block_reduce_sum(hin, scratch);

        if (tid == 0) {
            atomicAdd(&ws[0], -(ot - logZ));
            atomicAdd(&ws[1], hin);
            atomicAdd(&ws[2], lps);
            atomicAdd(&ws[3], ent);
            atomicAdd(&ws[4], sq);
        }
    }
}

// ---------------------------------------------------------------------------
// Final combine — 64x9 sigmoid-weighted sum, one block
// ---------------------------------------------------------------------------
__global__ __launch_bounds__(256) void final_kernel(
        const float* __restrict__ lw, const float* __restrict__ ws,
        float* __restrict__ out) {
    __shared__ float scratch[4];
    const float ce      = ws[0] / (float)BB;
    const float hinge   = ws[1] / ((float)BB * (float)CC);
    const float kl      = -logf((float)CC) - ws[2] / ((float)BB * (float)CC);
    const float entropy = -ws[3] / (float)BB;
    const float energy  = sqrtf(ws[4]);
    const float glob[5] = {ce, hinge, kl, entropy, energy};

    float acc = 0.f;
    for (int i = threadIdx.x; i < TT * NW; i += 256) {
        const int t = i / NW;
        const int k = i - t * NW;
        float cmb;
        if (k < 5)       cmb = glob[k];
        else if (k == 5) cmb = ws[8 + t * 4 + 0];
        else if (k == 6) cmb = sqrtf(ws[8 + t * 4 + 1]);
        else if (k == 7) cmb = ws[8 + t * 4 + 2];
        else             cmb = sqrtf(ws[8 + t * 4 + 3]);
        const float w = 1.f / (1.f + expf(-lw[i]));
        acc += w * cmb;
    }
    acc = block_reduce_sum(acc, scratch);
    if (threadIdx.x == 0) out[0] = acc / (float)(TT * NW);
}

// ---------------------------------------------------------------------------
extern "C" void kernel_launch(void* const* d_in, const int* in_sizes, int n_in,
                              void* d_out, int out_size, void* d_ws, size_t ws_size,
                              hipStream_t stream) {
    const float* outputs    = (const float*)d_in[0];
    const int*   targets    = (const int*)d_in[1];
    const float* params     = (const float*)d_in[2];
    const float* pretrained = (const float*)d_in[3];
    const float* lw         = (const float*)d_in[4];
    float* ws  = (float*)d_ws;
    float* out = (float*)d_out;

    hipMemsetAsync(ws, 0, WS_FLOATS * sizeof(float), stream);

    // 1984 param blocks (wave-sequential lines) + 512 logits blocks
    fused_kernel<<<PBLKS + BB, 256, 0, stream>>>(params, pretrained, outputs, targets, ws);
    final_kernel<<<1, 256, 0, stream>>>(lw, ws, out);
}

// Round 7
// 77.639 us; speedup vs baseline: 1.4182x; 1.4182x over previous
//
#include <hip/hip_runtime.h>
#include <hip/hip_bf16.h>
#include <math.h>

// Problem constants (from the reference)
#define BB 512        // batch
#define CC 1000       // classes
#define TT 64         // num param tensors
#define PSZ 500000    // elements per tensor
#define NW 9          // loss weights per tensor

// Param decomposition: 10 blocks per tensor, each a CONTIGUOUS chunk.
// 500000/10 = 50000 floats = 12500 float4 per block.
// 12500 = 3 * 4096 + 212  -> 3 bursts of (16 x 256 float4 = 64 KB) + tail.
#define BPT 10
#define PBLKS (TT * BPT)   // 640
#define C4 12500           // float4 per block chunk (blocks tile arrays exactly)
#define TAIL4 212          // 12500 - 3*4096

// Workspace layout (floats):
//  ws[0] = sum_b CE contribution    ws[1] = sum_b hinge row sums
//  ws[2] = sum_{b,j} logp           ws[3] = sum_b sum_j p*logp
//  ws[4] = sum_{b,j} o^2
//  ws[8 + t*4 + {0,1,2,3}] = {l1_zero, sumsq_zero, l1_pre, sumsq_pre}
#define WS_FLOATS (8 + TT * 4)

typedef float f32x4 __attribute__((ext_vector_type(4)));

__device__ __forceinline__ f32x4 ntload(const f32x4* a) {
    return __builtin_nontemporal_load(a);
}

// ---------------------------------------------------------------------------
__device__ __forceinline__ float block_reduce_sum(float v, float* scratch) {
    __syncthreads();
    for (int o = 32; o > 0; o >>= 1) v += __shfl_down(v, o);
    const int wave = threadIdx.x >> 6;
    if ((threadIdx.x & 63) == 0) scratch[wave] = v;
    __syncthreads();
    return scratch[0] + scratch[1] + scratch[2] + scratch[3];
}

__device__ __forceinline__ float block_reduce_max(float v, float* scratch) {
    __syncthreads();
    for (int o = 32; o > 0; o >>= 1) v = fmaxf(v, __shfl_down(v, o));
    const int wave = threadIdx.x >> 6;
    if ((threadIdx.x & 63) == 0) scratch[wave] = v;
    __syncthreads();
    return fmaxf(fmaxf(scratch[0], scratch[1]), fmaxf(scratch[2], scratch[3]));
}

__device__ __forceinline__ void acc4(const f32x4 a, const f32x4 c,
                                     float& l1z, float& s2z,
                                     float& l1p, float& s2p) {
    l1z += fabsf(a.x) + fabsf(a.y) + fabsf(a.z) + fabsf(a.w);
    s2z += a.x * a.x + a.y * a.y + a.z * a.z + a.w * a.w;
    const float dx = a.x - c.x, dy = a.y - c.y, dz = a.z - c.z, dw = a.w - c.w;
    l1p += fabsf(dx) + fabsf(dy) + fabsf(dz) + fabsf(dw);
    s2p += dx * dx + dy * dy + dz * dz + dw * dw;
}

// ---------------------------------------------------------------------------
// Fused kernel.
// Param path (blocks [0,640)): R5's winning block-contiguous layout with the
// burst deepened 32 KB -> 64 KB: 16 consecutive 1-KB-per-wave-line loads from
// p (one ascending 64 KB run), then the matching 64 KB from q consumed in
// groups of 4 (q issue order still one ascending 64 KB run; VALU only between
// groups). Run-length is the confirmed lever (R4 8KB-strided 107us,
// R6 8KB-seq 95us, R5 32KB 87us).
// Logits path: blocks [640, 1152).
// ---------------------------------------------------------------------------
__global__ __launch_bounds__(256, 2) void fused_kernel(
        const float* __restrict__ p, const float* __restrict__ q,
        const float* __restrict__ outlog, const int* __restrict__ tgt,
        float* __restrict__ ws) {
    __shared__ float row[CC];
    __shared__ float scratch[4];

    const int bid = blockIdx.x;
    const int tid = (int)threadIdx.x;
    if (bid < PBLKS) {
        // ---------------- param-norm path (256 MB total) -------------------
        const int t = bid / BPT;
        // blocks tile the arrays exactly: chunk base = bid * C4
        const f32x4* __restrict__ pb = (const f32x4*)p + (long long)bid * C4;
        const f32x4* __restrict__ qb = (const f32x4*)q + (long long)bid * C4;

        float l1z = 0.f, s2z = 0.f, l1p = 0.f, s2p = 0.f;

        #pragma unroll 1
        for (int j = 0; j < 3; ++j) {
            const f32x4* bp = pb + j * 4096 + tid;
            const f32x4* bq = qb + j * 4096 + tid;
            f32x4 A[16];
            #pragma unroll
            for (int k = 0; k < 16; ++k) A[k] = ntload(bp + k * 256);
            #pragma unroll
            for (int g = 0; g < 4; ++g) {
                f32x4 Cg[4];
                #pragma unroll
                for (int k = 0; k < 4; ++k) Cg[k] = ntload(bq + (g * 4 + k) * 256);
                #pragma unroll
                for (int k = 0; k < 4; ++k)
                    acc4(A[g * 4 + k], Cg[k], l1z, s2z, l1p, s2p);
            }
        }
        // tail: 212 float4 at chunk offset 12288
        if (tid < TAIL4) {
            const f32x4 a = ntload(pb + 3 * 4096 + tid);
            const f32x4 c = ntload(qb + 3 * 4096 + tid);
            acc4(a, c, l1z, s2z, l1p, s2p);
        }

        for (int o = 32; o > 0; o >>= 1) {
            l1z += __shfl_down(l1z, o);
            s2z += __shfl_down(s2z, o);
            l1p += __shfl_down(l1p, o);
            s2p += __shfl_down(s2p, o);
        }
        if ((tid & 63) == 0) {
            float* base = ws + 8 + t * 4;
            atomicAdd(base + 0, l1z);
            atomicAdd(base + 1, s2z);
            atomicAdd(base + 2, l1p);
            atomicAdd(base + 3, s2p);
        }
    } else {
        // ---------------- logits path (one block per batch row) ------------
        const int b = bid - PBLKS;
        const float* __restrict__ o = outlog + (long long)b * CC;

        float sq = 0.f;
        for (int j = tid; j < CC; j += 256) {
            const float v = o[j];
            row[j] = v;
            sq += v * v;
        }
        __syncthreads();

        float m = -3.402823466e+38f;
        for (int j = tid; j < CC; j += 256) m = fmaxf(m, row[j]);
        m = block_reduce_max(m, scratch);

        float se = 0.f;
        for (int j = tid; j < CC; j += 256) se += __expf(row[j] - m);
        se = block_reduce_sum(se, scratch);
        const float logZ = m + __logf(se);

        const int tg = tgt[b];
        const float ot = row[tg];

        float ent = 0.f, lps = 0.f, hin = 0.f;
        for (int j = tid; j < CC; j += 256) {
            const float lp = row[j] - logZ;
            ent += __expf(lp) * lp;
            lps += lp;
            const float mg = 1.f - ot + row[j];
            if (j != tg && mg > 0.f) hin += mg;
        }
        sq  = block_reduce_sum(sq, scratch);
        ent = block_reduce_sum(ent, scratch);
        lps = block_reduce_sum(lps, scratch);
        hin = block_reduce_sum(hin, scratch);

        if (tid == 0) {
            atomicAdd(&ws[0], -(ot - logZ));
            atomicAdd(&ws[1], hin);
            atomicAdd(&ws[2], lps);
            atomicAdd(&ws[3], ent);
            atomicAdd(&ws[4], sq);
        }
    }
}

// ---------------------------------------------------------------------------
// Final combine — 64x9 sigmoid-weighted sum, one block
// ---------------------------------------------------------------------------
__global__ __launch_bounds__(256) void final_kernel(
        const float* __restrict__ lw, const float* __restrict__ ws,
        float* __restrict__ out) {
    __shared__ float scratch[4];
    const float ce      = ws[0] / (float)BB;
    const float hinge   = ws[1] / ((float)BB * (float)CC);
    const float kl      = -logf((float)CC) - ws[2] / ((float)BB * (float)CC);
    const float entropy = -ws[3] / (float)BB;
    const float energy  = sqrtf(ws[4]);
    const float glob[5] = {ce, hinge, kl, entropy, energy};

    float acc = 0.f;
    for (int i = threadIdx.x; i < TT * NW; i += 256) {
        const int t = i / NW;
        const int k = i - t * NW;
        float cmb;
        if (k < 5)       cmb = glob[k];
        else if (k == 5) cmb = ws[8 + t * 4 + 0];
        else if (k == 6) cmb = sqrtf(ws[8 + t * 4 + 1]);
        else if (k == 7) cmb = ws[8 + t * 4 + 2];
        else             cmb = sqrtf(ws[8 + t * 4 + 3]);
        const float w = 1.f / (1.f + expf(-lw[i]));
        acc += w * cmb;
    }
    acc = block_reduce_sum(acc, scratch);
    if (threadIdx.x == 0) out[0] = acc / (float)(TT * NW);
}

// ---------------------------------------------------------------------------
extern "C" void kernel_launch(void* const* d_in, const int* in_sizes, int n_in,
                              void* d_out, int out_size, void* d_ws, size_t ws_size,
                              hipStream_t stream) {
    const float* outputs    = (const float*)d_in[0];
    const int*   targets    = (const int*)d_in[1];
    const float* params     = (const float*)d_in[2];
    const float* pretrained = (const float*)d_in[3];
    const float* lw         = (const float*)d_in[4];
    float* ws  = (float*)d_ws;
    float* out = (float*)d_out;

    hipMemsetAsync(ws, 0, WS_FLOATS * sizeof(float), stream);

    // 640 param blocks (64 KB runs) + 512 logits blocks
    fused_kernel<<<PBLKS + BB, 256, 0, stream>>>(params, pretrained, outputs, targets, ws);
    final_kernel<<<1, 256, 0, stream>>>(lw, ws, out);
}

// Round 8
// 76.968 us; speedup vs baseline: 1.4305x; 1.0087x over previous
//
#include <hip/hip_runtime.h>
#include <hip/hip_bf16.h>
#include <math.h>

// Problem constants (from the reference)
#define BB 512        // batch
#define CC 1000       // classes
#define TT 64         // num param tensors
#define PSZ 500000    // elements per tensor
#define NW 9          // loss weights per tensor

// Param decomposition: 5 blocks per tensor, each a CONTIGUOUS chunk.
// 500000/5 = 100000 floats = 25000 float4 per block.
// 25000 = 3 * 8192 + 424  -> 3 bursts of (32 x 256 float4 = 128 KB) + tail.
#define BPT 5
#define PBLKS (TT * BPT)   // 320
#define C4 25000           // float4 per block chunk (blocks tile arrays exactly)
#define TAIL4 424          // 25000 - 3*8192

// Workspace layout (floats):
//  ws[0] = sum_b CE contribution    ws[1] = sum_b hinge row sums
//  ws[2] = sum_{b,j} logp           ws[3] = sum_b sum_j p*logp
//  ws[4] = sum_{b,j} o^2
//  ws[8 + t*4 + {0,1,2,3}] = {l1_zero, sumsq_zero, l1_pre, sumsq_pre}
#define WS_FLOATS (8 + TT * 4)

typedef float f32x4 __attribute__((ext_vector_type(4)));

__device__ __forceinline__ f32x4 ntload(const f32x4* a) {
    return __builtin_nontemporal_load(a);
}

// ---------------------------------------------------------------------------
__device__ __forceinline__ float block_reduce_sum(float v, float* scratch) {
    __syncthreads();
    for (int o = 32; o > 0; o >>= 1) v += __shfl_down(v, o);
    const int wave = threadIdx.x >> 6;
    if ((threadIdx.x & 63) == 0) scratch[wave] = v;
    __syncthreads();
    return scratch[0] + scratch[1] + scratch[2] + scratch[3];
}

__device__ __forceinline__ float block_reduce_max(float v, float* scratch) {
    __syncthreads();
    for (int o = 32; o > 0; o >>= 1) v = fmaxf(v, __shfl_down(v, o));
    const int wave = threadIdx.x >> 6;
    if ((threadIdx.x & 63) == 0) scratch[wave] = v;
    __syncthreads();
    return fmaxf(fmaxf(scratch[0], scratch[1]), fmaxf(scratch[2], scratch[3]));
}

__device__ __forceinline__ void acc4(const f32x4 a, const f32x4 c,
                                     float& l1z, float& s2z,
                                     float& l1p, float& s2p) {
    l1z += fabsf(a.x) + fabsf(a.y) + fabsf(a.z) + fabsf(a.w);
    s2z += a.x * a.x + a.y * a.y + a.z * a.z + a.w * a.w;
    const float dx = a.x - c.x, dy = a.y - c.y, dz = a.z - c.z, dw = a.w - c.w;
    l1p += fabsf(dx) + fabsf(dy) + fabsf(dz) + fabsf(dw);
    s2p += dx * dx + dy * dy + dz * dz + dw * dw;
}

// ---------------------------------------------------------------------------
// Fused kernel.
// Param path (blocks [0,320)): R7's winning structure with the burst deepened
// 64 KB -> 128 KB: 32 consecutive 1-KB wave-line loads from p (one ascending
// 128 KB run), then the matching 128 KB from q consumed in groups of 4
// (q issue order still one ascending run). Run length is the confirmed lever:
// 8KB-strided 107us -> 8KB-seq 95us -> 32KB 87us -> 64KB ~72us.
// __launch_bounds__(256,1): VGPR cap 512 so the 32-deep A batch (128 VGPRs)
// materializes; occupancy is proven irrelevant (R1-R4: flat from 10-68%).
// Logits path: blocks [320, 832).
// ---------------------------------------------------------------------------
__global__ __launch_bounds__(256, 1) void fused_kernel(
        const float* __restrict__ p, const float* __restrict__ q,
        const float* __restrict__ outlog, const int* __restrict__ tgt,
        float* __restrict__ ws) {
    __shared__ float row[CC];
    __shared__ float scratch[4];

    const int bid = blockIdx.x;
    const int tid = (int)threadIdx.x;
    if (bid < PBLKS) {
        // ---------------- param-norm path (256 MB total) -------------------
        const int t = bid / BPT;
        // blocks tile the arrays exactly: chunk base = bid * C4
        const f32x4* __restrict__ pb = (const f32x4*)p + (long long)bid * C4;
        const f32x4* __restrict__ qb = (const f32x4*)q + (long long)bid * C4;

        float l1z = 0.f, s2z = 0.f, l1p = 0.f, s2p = 0.f;

        #pragma unroll 1
        for (int j = 0; j < 3; ++j) {
            const f32x4* bp = pb + j * 8192 + tid;
            const f32x4* bq = qb + j * 8192 + tid;
            f32x4 A[32];
            #pragma unroll
            for (int k = 0; k < 32; ++k) A[k] = ntload(bp + k * 256);
            #pragma unroll
            for (int g = 0; g < 8; ++g) {
                f32x4 Cg[4];
                #pragma unroll
                for (int k = 0; k < 4; ++k) Cg[k] = ntload(bq + (g * 4 + k) * 256);
                #pragma unroll
                for (int k = 0; k < 4; ++k)
                    acc4(A[g * 4 + k], Cg[k], l1z, s2z, l1p, s2p);
            }
        }
        // tail: 424 float4 at chunk offset 24576
        if (tid < TAIL4) {
            const f32x4 a = ntload(pb + 3 * 8192 + tid);
            const f32x4 c = ntload(qb + 3 * 8192 + tid);
            acc4(a, c, l1z, s2z, l1p, s2p);
        }

        for (int o = 32; o > 0; o >>= 1) {
            l1z += __shfl_down(l1z, o);
            s2z += __shfl_down(s2z, o);
            l1p += __shfl_down(l1p, o);
            s2p += __shfl_down(s2p, o);
        }
        if ((tid & 63) == 0) {
            float* base = ws + 8 + t * 4;
            atomicAdd(base + 0, l1z);
            atomicAdd(base + 1, s2z);
            atomicAdd(base + 2, l1p);
            atomicAdd(base + 3, s2p);
        }
    } else {
        // ---------------- logits path (one block per batch row) ------------
        const int b = bid - PBLKS;
        const float* __restrict__ o = outlog + (long long)b * CC;

        float sq = 0.f;
        for (int j = tid; j < CC; j += 256) {
            const float v = o[j];
            row[j] = v;
            sq += v * v;
        }
        __syncthreads();

        float m = -3.402823466e+38f;
        for (int j = tid; j < CC; j += 256) m = fmaxf(m, row[j]);
        m = block_reduce_max(m, scratch);

        float se = 0.f;
        for (int j = tid; j < CC; j += 256) se += __expf(row[j] - m);
        se = block_reduce_sum(se, scratch);
        const float logZ = m + __logf(se);

        const int tg = tgt[b];
        const float ot = row[tg];

        float ent = 0.f, lps = 0.f, hin = 0.f;
        for (int j = tid; j < CC; j += 256) {
            const float lp = row[j] - logZ;
            ent += __expf(lp) * lp;
            lps += lp;
            const float mg = 1.f - ot + row[j];
            if (j != tg && mg > 0.f) hin += mg;
        }
        sq  = block_reduce_sum(sq, scratch);
        ent = block_reduce_sum(ent, scratch);
        lps = block_reduce_sum(lps, scratch);
        hin = block_reduce_sum(hin, scratch);

        if (tid == 0) {
            atomicAdd(&ws[0], -(ot - logZ));
            atomicAdd(&ws[1], hin);
            atomicAdd(&ws[2], lps);
            atomicAdd(&ws[3], ent);
            atomicAdd(&ws[4], sq);
        }
    }
}

// ---------------------------------------------------------------------------
// Final combine — 64x9 sigmoid-weighted sum, one block
// ---------------------------------------------------------------------------
__global__ __launch_bounds__(256) void final_kernel(
        const float* __restrict__ lw, const float* __restrict__ ws,
        float* __restrict__ out) {
    __shared__ float scratch[4];
    const float ce      = ws[0] / (float)BB;
    const float hinge   = ws[1] / ((float)BB * (float)CC);
    const float kl      = -logf((float)CC) - ws[2] / ((float)BB * (float)CC);
    const float entropy = -ws[3] / (float)BB;
    const float energy  = sqrtf(ws[4]);
    const float glob[5] = {ce, hinge, kl, entropy, energy};

    float acc = 0.f;
    for (int i = threadIdx.x; i < TT * NW; i += 256) {
        const int t = i / NW;
        const int k = i - t * NW;
        float cmb;
        if (k < 5)       cmb = glob[k];
        else if (k == 5) cmb = ws[8 + t * 4 + 0];
        else if (k == 6) cmb = sqrtf(ws[8 + t * 4 + 1]);
        else if (k == 7) cmb = ws[8 + t * 4 + 2];
        else             cmb = sqrtf(ws[8 + t * 4 + 3]);
        const float w = 1.f / (1.f + expf(-lw[i]));
        acc += w * cmb;
    }
    acc = block_reduce_sum(acc, scratch);
    if (threadIdx.x == 0) out[0] = acc / (float)(TT * NW);
}

// ---------------------------------------------------------------------------
extern "C" void kernel_launch(void* const* d_in, const int* in_sizes, int n_in,
                              void* d_out, int out_size, void* d_ws, size_t ws_size,
                              hipStream_t stream) {
    const float* outputs    = (const float*)d_in[0];
    const int*   targets    = (const int*)d_in[1];
    const float* params     = (const float*)d_in[2];
    const float* pretrained = (const float*)d_in[3];
    const float* lw         = (const float*)d_in[4];
    float* ws  = (float*)d_ws;
    float* out = (float*)d_out;

    hipMemsetAsync(ws, 0, WS_FLOATS * sizeof(float), stream);

    // 320 param blocks (128 KB runs) + 512 logits blocks
    fused_kernel<<<PBLKS + BB, 256, 0, stream>>>(params, pretrained, outputs, targets, ws);
    final_kernel<<<1, 256, 0, stream>>>(lw, ws, out);
}